// Round 1
// baseline (536.080 us; speedup 1.0000x reference)
//
#include <hip/hip_runtime.h>

#define D_ 64
#define L_ 2
#define R_ 50
#define N_ 20001
#define A_ 6
#define E_ 30000
#define B_ 4
#define C_ 500
#define FEAT_ 128

// ---------- helpers ----------

__device__ __forceinline__ float rlane(float v, int k) {
  return __builtin_bit_cast(float, __builtin_amdgcn_readlane(__builtin_bit_cast(int, v), k));
}

__device__ __forceinline__ float wave_sum(float v) {
#pragma unroll
  for (int off = 32; off; off >>= 1) v += __shfl_xor(v, off);
  return v;
}

// ---------- init: pos_search detection + seed scatter ----------

__global__ void init_kernel(const int* __restrict__ r_idx, const int* __restrict__ ents,
                            const int* __restrict__ arity,
                            const float* __restrict__ pos_table,
                            const float* __restrict__ query_emb,
                            float* __restrict__ h, int* __restrict__ meta) {
  int b = blockIdx.x;
  int t = threadIdx.x;
  __shared__ int diff[A_];
  if (t < A_) diff[t] = 0;
  __syncthreads();
#pragma unroll
  for (int a = 0; a < A_; ++a) {
    int v0 = ents[(b * C_) * A_ + a];
    int dd = 0;
    for (int c = t; c < C_; c += blockDim.x)
      dd |= (ents[(b * C_ + c) * A_ + a] != v0);
    if (dd) diff[a] = 1;
  }
  __syncthreads();
  int ps = 0;
  for (int a = A_ - 1; a >= 0; --a)
    if (diff[a]) ps = a;
  int qr = r_idx[b * C_];
  if (t == 0) { meta[b] = ps; meta[B_ + b] = qr; }
  int ar = arity[b * C_];
  int lane = t & 63;
  for (int a = (t >> 6); a < A_; a += 4) {
    if (a < ar && a != ps) {
      int n = ents[(b * C_) * A_ + a];
      float val = query_emb[qr * D_ + lane] + pos_table[(a + 1) * D_ + lane];
      atomicAdd(&h[(b * N_ + n) * D_ + lane], val);
    }
  }
}

// ---------- CSR build (node -> incident (edge,pos) pairs) ----------

__global__ void count_kernel(const int* __restrict__ edge_list, int* __restrict__ cnt) {
  int i = blockIdx.x * blockDim.x + threadIdx.x;
  if (i >= E_ * A_) return;
  int n = edge_list[i];
  if (n) atomicAdd(&cnt[n], 1);
}

#define SCAN_T 1024
#define CHUNK 20
__global__ void scan_kernel(const int* __restrict__ cnt, int* __restrict__ off,
                            int* __restrict__ cur) {
  __shared__ int part[SCAN_T];
  int t = threadIdx.x;
  int base = t * CHUNK;
  int v[CHUNK];
  int s = 0;
#pragma unroll
  for (int i = 0; i < CHUNK; ++i) {
    int idx = base + i;
    v[i] = (idx < N_) ? cnt[idx] : 0;
    s += v[i];
  }
  part[t] = s;
  __syncthreads();
  for (int d = 1; d < SCAN_T; d <<= 1) {
    int x = part[t];
    int y = (t >= d) ? part[t - d] : 0;
    __syncthreads();
    part[t] = x + y;
    __syncthreads();
  }
  int run = (t == 0) ? 0 : part[t - 1];
#pragma unroll
  for (int i = 0; i < CHUNK; ++i) {
    int idx = base + i;
    if (idx < N_) {
      off[idx] = run;
      cur[idx] = run;
      run += v[i];
    }
  }
  if (t == SCAN_T - 1) off[N_] = part[SCAN_T - 1];
}

__global__ void fill_kernel(const int* __restrict__ edge_list, int* __restrict__ cur,
                            int* __restrict__ pairs) {
  int i = blockIdx.x * blockDim.x + threadIdx.x;
  if (i >= E_ * A_) return;
  int n = edge_list[i];
  if (n) {
    int p = atomicAdd(&cur[n], 1);
    pairs[p] = i;
  }
}

// ---------- per-edge sums S[b,e,:] ----------

__global__ __launch_bounds__(256) void s_kernel(const int* __restrict__ edge_list,
                                                const int* __restrict__ rel_list,
                                                const float* __restrict__ pos_table,
                                                const float* __restrict__ rel_emb_l,
                                                const float* __restrict__ h,
                                                float* __restrict__ S) {
  int w = (blockIdx.x * blockDim.x + threadIdx.x) >> 6;
  int lane = threadIdx.x & 63;
  if (w >= E_ * B_) return;
  int e = w >> 2;
  int b = w & 3;
  float rel = rel_emb_l[rel_list[e] * D_ + lane];
  float s = 0.f;
#pragma unroll
  for (int a = 0; a < A_; ++a) {
    int n = edge_list[e * A_ + a];
    if (n) s += (h[(b * N_ + n) * D_ + lane] + pos_table[(a + 1) * D_ + lane]) * rel;
  }
  S[w * D_ + lane] = s;
}

// ---------- fused node update: CSR-agg + dual matvec + LN + ReLU + residual ----------

__global__ __launch_bounds__(256) void node_kernel(
    const int* __restrict__ csr_off, const int* __restrict__ pairs,
    const int* __restrict__ rel_list,
    const float* __restrict__ pos_table, const float* __restrict__ rel_emb_l,
    const float* __restrict__ S, float* __restrict__ h,
    const float* __restrict__ W_agg_l, const float* __restrict__ W_self_l,
    const float* __restrict__ b_lin_l, const float* __restrict__ ln_g_l,
    const float* __restrict__ ln_b_l) {
  int lane = threadIdx.x & 63;
  float wa[D_], wsf[D_];
#pragma unroll
  for (int k = 0; k < D_; ++k) {
    wa[k] = W_agg_l[k * D_ + lane];
    wsf[k] = W_self_l[k * D_ + lane];
  }
  float bl = b_lin_l[lane], g = ln_g_l[lane], bb = ln_b_l[lane];
  int w0 = (blockIdx.x * blockDim.x + threadIdx.x) >> 6;
  int nw = (gridDim.x * blockDim.x) >> 6;
  for (int r = w0; r < B_ * N_; r += nw) {
    int n = r >> 2;
    int b = r & 3;
    int p0 = csr_off[n], p1 = csr_off[n + 1];
    float hv = h[(b * N_ + n) * D_ + lane];
    float aggv = 0.f;
    for (int p = p0; p < p1; ++p) {
      int i = pairs[p];
      unsigned e = (unsigned)i / 6u;
      unsigned a = (unsigned)i - e * 6u;
      float rel = rel_emb_l[rel_list[e] * D_ + lane];
      float sv = S[(e * 4u + (unsigned)b) * D_ + lane];
      aggv += sv - (hv + pos_table[(a + 1) * D_ + lane]) * rel;
    }
    float out = bl;
#pragma unroll
    for (int k = 0; k < D_; ++k) {
      out = fmaf(rlane(aggv, k), wa[k], out);
      out = fmaf(rlane(hv, k), wsf[k], out);
    }
    float mu = wave_sum(out) * (1.f / 64.f);
    float dx = out - mu;
    float var = wave_sum(dx * dx) * (1.f / 64.f);
    float y = dx * rsqrtf(var + 1e-5f) * g + bb;
    h[(b * N_ + n) * D_ + lane] = fmaxf(y, 0.f) + hv;
  }
}

// ---------- scoring MLP ----------

__global__ __launch_bounds__(256) void score_kernel(
    const int* __restrict__ ents, const float* __restrict__ h,
    const int* __restrict__ meta, const float* __restrict__ query_emb,
    const float* __restrict__ W1, const float* __restrict__ b1,
    const float* __restrict__ W2, const float* __restrict__ b2,
    float* __restrict__ out) {
  int w = (blockIdx.x * blockDim.x + threadIdx.x) >> 6;
  int lane = threadIdx.x & 63;
  if (w >= B_ * C_) return;
  int b = w / C_;
  int c = w - b * C_;
  int ps = meta[b];
  int qr = meta[B_ + b];
  int cand = ents[(b * C_ + c) * A_ + ps];
  float fv = h[(b * N_ + cand) * D_ + lane];
  float qv = query_emb[qr * D_ + lane];
  float hid0 = b1[lane];
  float hid1 = b1[D_ + lane];
#pragma unroll
  for (int k = 0; k < D_; ++k) {
    float f = rlane(fv, k);
    hid0 = fmaf(f, W1[k * FEAT_ + lane], hid0);
    hid1 = fmaf(f, W1[k * FEAT_ + D_ + lane], hid1);
  }
#pragma unroll
  for (int k = 0; k < D_; ++k) {
    float q = rlane(qv, k);
    hid0 = fmaf(q, W1[(D_ + k) * FEAT_ + lane], hid0);
    hid1 = fmaf(q, W1[(D_ + k) * FEAT_ + D_ + lane], hid1);
  }
  float acc = fmaxf(hid0, 0.f) * W2[lane] + fmaxf(hid1, 0.f) * W2[D_ + lane];
  acc = wave_sum(acc);
  if (lane == 0) out[w] = acc + b2[0];
}

// ---------- launch ----------

extern "C" void kernel_launch(void* const* d_in, const int* in_sizes, int n_in,
                              void* d_out, int out_size, void* d_ws, size_t ws_size,
                              hipStream_t stream) {
  const int* r_idx = (const int*)d_in[0];
  const int* ents = (const int*)d_in[1];
  const int* arity = (const int*)d_in[2];
  const int* edge_list = (const int*)d_in[3];
  const int* rel_list = (const int*)d_in[4];
  const float* pos_table = (const float*)d_in[5];
  const float* query_emb = (const float*)d_in[6];
  const float* rel_emb = (const float*)d_in[7];
  const float* W_agg = (const float*)d_in[8];
  const float* W_self = (const float*)d_in[9];
  const float* b_lin = (const float*)d_in[10];
  const float* ln_g = (const float*)d_in[11];
  const float* ln_b = (const float*)d_in[12];
  const float* W1 = (const float*)d_in[13];
  const float* b1 = (const float*)d_in[14];
  const float* W2 = (const float*)d_in[15];
  const float* b2 = (const float*)d_in[16];
  float* out = (float*)d_out;

  char* ws = (char*)d_ws;
  const size_t H_BYTES = (size_t)B_ * N_ * D_ * 4;  // 20,481,024
  const size_t S_BYTES = (size_t)E_ * B_ * D_ * 4;  // 30,720,000
  float* h = (float*)ws;
  float* S = (float*)(ws + 20481024);
  int* cnt = (int*)(ws + 51201024);       // 20002 ints
  int* csr_off = (int*)(ws + 51281152);   // 20002 ints
  int* csr_cur = (int*)(ws + 51361280);   // 20002 ints
  int* pairs = (int*)(ws + 51441408);     // up to 180000 ints
  int* meta = (int*)(ws + 52161408);      // 8 ints
  if (ws_size < 52161440) return;  // insufficient scratch; bail loudly (output stays poisoned)

  hipMemsetAsync(h, 0, H_BYTES, stream);
  hipMemsetAsync(cnt, 0, (N_ + 1) * sizeof(int), stream);

  init_kernel<<<B_, 256, 0, stream>>>(r_idx, ents, arity, pos_table, query_emb, h, meta);
  count_kernel<<<(E_ * A_ + 255) / 256, 256, 0, stream>>>(edge_list, cnt);
  scan_kernel<<<1, SCAN_T, 0, stream>>>(cnt, csr_off, csr_cur);
  fill_kernel<<<(E_ * A_ + 255) / 256, 256, 0, stream>>>(edge_list, csr_cur, pairs);

  for (int l = 0; l < L_; ++l) {
    s_kernel<<<E_ * B_ / 4, 256, 0, stream>>>(edge_list, rel_list, pos_table,
                                              rel_emb + l * R_ * D_, h, S);
    node_kernel<<<2048, 256, 0, stream>>>(csr_off, pairs, rel_list, pos_table,
                                          rel_emb + l * R_ * D_, S, h,
                                          W_agg + l * D_ * D_, W_self + l * D_ * D_,
                                          b_lin + l * D_, ln_g + l * D_, ln_b + l * D_);
  }

  score_kernel<<<(B_ * C_ + 3) / 4, 256, 0, stream>>>(ents, h, meta, query_emb,
                                                      W1, b1, W2, b2, out);
  (void)in_sizes; (void)n_in; (void)out_size; (void)S_BYTES;
}

// Round 2
// 488.550 us; speedup vs baseline: 1.0973x; 1.0973x over previous
//
#include <hip/hip_runtime.h>

#define D_ 64
#define L_ 2
#define R_ 50
#define N_ 20001
#define A_ 6
#define E_ 30000
#define B_ 4
#define C_ 500
#define FEAT_ 128
#define MROWS (N_ * B_)  // 80004

__device__ __forceinline__ float rlane(float v, int k) {
  return __builtin_bit_cast(float, __builtin_amdgcn_readlane(__builtin_bit_cast(int, v), k));
}

__device__ __forceinline__ float wave_sum(float v) {
#pragma unroll
  for (int off = 32; off; off >>= 1) v += __shfl_xor(v, off);
  return v;
}

// ---------- init: pos_search detection + seed scatter (h layout [n][b][d]) ----------

__global__ void init_kernel(const int* __restrict__ r_idx, const int* __restrict__ ents,
                            const int* __restrict__ arity,
                            const float* __restrict__ pos_table,
                            const float* __restrict__ query_emb,
                            float* __restrict__ h, int* __restrict__ meta) {
  int b = blockIdx.x;
  int t = threadIdx.x;
  __shared__ int diff[A_];
  if (t < A_) diff[t] = 0;
  __syncthreads();
#pragma unroll
  for (int a = 0; a < A_; ++a) {
    int v0 = ents[(b * C_) * A_ + a];
    int dd = 0;
    for (int c = t; c < C_; c += blockDim.x)
      dd |= (ents[(b * C_ + c) * A_ + a] != v0);
    if (dd) diff[a] = 1;
  }
  __syncthreads();
  int ps = 0;
  for (int a = A_ - 1; a >= 0; --a)
    if (diff[a]) ps = a;
  int qr = r_idx[b * C_];
  if (t == 0) { meta[b] = ps; meta[B_ + b] = qr; }
  int ar = arity[b * C_];
  int lane = t & 63;
  for (int a = (t >> 6); a < A_; a += 4) {
    if (a < ar && a != ps) {
      int n = ents[(b * C_) * A_ + a];
      float val = query_emb[qr * D_ + lane] + pos_table[(a + 1) * D_ + lane];
      atomicAdd(&h[(n * B_ + b) * D_ + lane], val);
    }
  }
}

// ---------- CSR build (node -> incident (edge,pos) pairs) ----------

__global__ void count_kernel(const int* __restrict__ edge_list, int* __restrict__ cnt) {
  int i = blockIdx.x * blockDim.x + threadIdx.x;
  if (i >= E_ * A_) return;
  int n = edge_list[i];
  if (n) atomicAdd(&cnt[n], 1);
}

#define SCAN_T 1024
#define CHUNK 20
// reads cnt, writes off; overwrites cnt with running offsets (reused as cursor)
__global__ void scan_kernel(int* __restrict__ cnt, int* __restrict__ off) {
  __shared__ int part[SCAN_T];
  int t = threadIdx.x;
  int base = t * CHUNK;
  int v[CHUNK];
  int s = 0;
#pragma unroll
  for (int i = 0; i < CHUNK; ++i) {
    int idx = base + i;
    v[i] = (idx < N_) ? cnt[idx] : 0;
    s += v[i];
  }
  part[t] = s;
  __syncthreads();
  for (int d = 1; d < SCAN_T; d <<= 1) {
    int x = part[t];
    int y = (t >= d) ? part[t - d] : 0;
    __syncthreads();
    part[t] = x + y;
    __syncthreads();
  }
  int run = (t == 0) ? 0 : part[t - 1];
#pragma unroll
  for (int i = 0; i < CHUNK; ++i) {
    int idx = base + i;
    if (idx < N_) {
      off[idx] = run;
      cnt[idx] = run;  // cursor
      run += v[i];
    }
  }
  if (t == SCAN_T - 1) off[N_] = part[SCAN_T - 1];
}

__global__ void fill_kernel(const int* __restrict__ edge_list, int* __restrict__ cur,
                            int* __restrict__ pairs) {
  int i = blockIdx.x * blockDim.x + threadIdx.x;
  if (i >= E_ * A_) return;
  int n = edge_list[i];
  if (n) {
    int p = atomicAdd(&cur[n], 1);
    pairs[p] = i;
  }
}

// ---------- per-node batch-independent sums: rel_sum, pr_sum ----------

__global__ __launch_bounds__(256) void rs_kernel(
    const int* __restrict__ csr_off, const int* __restrict__ pairs,
    const int* __restrict__ rel_list, const float* __restrict__ pos_table,
    const float* __restrict__ rel_emb_l,
    float* __restrict__ rel_sum, float* __restrict__ pr_sum) {
  int n = blockIdx.x * 4 + (threadIdx.x >> 6);
  int lane = threadIdx.x & 63;
  if (n >= N_) return;
  int p0 = csr_off[n], p1 = csr_off[n + 1];
  float rs = 0.f, ps = 0.f;
  for (int p = p0; p < p1; ++p) {
    int i = pairs[p];
    int e = i / 6, a = i - e * 6;
    float r = rel_emb_l[rel_list[e] * D_ + lane];
    rs += r;
    ps += pos_table[(a + 1) * D_ + lane] * r;
  }
  rel_sum[n * D_ + lane] = rs;
  pr_sum[n * D_ + lane] = ps;
}

// ---------- agg via direct neighbor gather ----------
// agg[n,b] = sum_{(e,a) incident n} S_e[b]  -  h[n,b]*rel_sum[n] - pr_sum[n]
// S_e[b] = rel_e * sum_{a': n'!=0} (h[n',b] + pos[a'+1])

__global__ __launch_bounds__(256) void agg_kernel(
    const int* __restrict__ csr_off, const int* __restrict__ pairs,
    const int* __restrict__ edge_list, const int* __restrict__ rel_list,
    const float* __restrict__ pos_table, const float* __restrict__ rel_emb_l,
    const float* __restrict__ h, const float* __restrict__ rel_sum,
    const float* __restrict__ pr_sum, float* __restrict__ agg) {
  int n = blockIdx.x;
  int b = threadIdx.x >> 6;
  int lane = threadIdx.x & 63;
  int p0 = csr_off[n], p1 = csr_off[n + 1];
  float hv = h[(n * B_ + b) * D_ + lane];
  float acc = 0.f;
  for (int p = p0; p < p1; ++p) {
    int i = pairs[p];
    int e = i / 6;
    const int* en = &edge_list[e * A_];
    float rel = rel_emb_l[rel_list[e] * D_ + lane];
    float s = 0.f;
#pragma unroll
    for (int a2 = 0; a2 < A_; ++a2) {
      int n2 = en[a2];
      if (n2) s += h[(n2 * B_ + b) * D_ + lane] + pos_table[(a2 + 1) * D_ + lane];
    }
    acc = fmaf(s, rel, acc);
  }
  agg[(n * B_ + b) * D_ + lane] =
      acc - hv * rel_sum[n * D_ + lane] - pr_sum[n * D_ + lane];
}

// ---------- tiled SGEMM (M=80004, K=128 split 2x64, N=64) + LN + ReLU + residual ----------

__global__ __launch_bounds__(256) void sgemm_kernel(
    const float* __restrict__ agg, float* __restrict__ h,
    const float* __restrict__ W_agg_l, const float* __restrict__ W_self_l,
    const float* __restrict__ b_lin_l, const float* __restrict__ ln_g_l,
    const float* __restrict__ ln_b_l) {
  __shared__ float A_lds[64 * 68];  // [r][68], pad 4 -> conflict-light
  __shared__ float B_lds[64 * 64];  // [k][c]
  int t = threadIdx.x;
  int m0 = blockIdx.x * 64;
  int ty = t >> 4, tx = t & 15;

  float acc[4][4];
  float4 bl = *reinterpret_cast<const float4*>(&b_lin_l[tx * 4]);
#pragma unroll
  for (int i = 0; i < 4; ++i) {
    acc[i][0] = bl.x; acc[i][1] = bl.y; acc[i][2] = bl.z; acc[i][3] = bl.w;
  }

  for (int half = 0; half < 2; ++half) {
    const float* Asrc = half ? h : agg;
    const float* Wsrc = half ? W_self_l : W_agg_l;
    // stage A half-tile: 64 rows x 64 k (float4 loads+stores, conflict-free)
#pragma unroll
    for (int it = 0; it < 4; ++it) {
      int idx4 = t + 256 * it;  // 0..1023
      int r = idx4 >> 4, kq = idx4 & 15;
      int row = m0 + r;
      float4 v = make_float4(0.f, 0.f, 0.f, 0.f);
      if (row < MROWS) v = *reinterpret_cast<const float4*>(&Asrc[row * 64 + kq * 4]);
      *reinterpret_cast<float4*>(&A_lds[r * 68 + kq * 4]) = v;
    }
    // stage B half: 64 k x 64 c
#pragma unroll
    for (int it = 0; it < 16; ++it) {
      int idx = t + 256 * it;  // 0..4095
      int k = idx >> 6, c = idx & 63;
      B_lds[k * 64 + c] = Wsrc[k * 64 + c];
    }
    __syncthreads();
#pragma unroll 8
    for (int k = 0; k < 64; ++k) {
      float4 b4 = *reinterpret_cast<const float4*>(&B_lds[k * 64 + tx * 4]);
      float bv[4] = {b4.x, b4.y, b4.z, b4.w};
      float av[4];
#pragma unroll
      for (int i = 0; i < 4; ++i) av[i] = A_lds[(ty * 4 + i) * 68 + k];
#pragma unroll
      for (int i = 0; i < 4; ++i)
#pragma unroll
        for (int j = 0; j < 4; ++j)
          acc[i][j] = fmaf(av[i], bv[j], acc[i][j]);
    }
    __syncthreads();
  }

  // stage out tile into A_lds region: [r][68]
#pragma unroll
  for (int i = 0; i < 4; ++i) {
    float4 v = make_float4(acc[i][0], acc[i][1], acc[i][2], acc[i][3]);
    *reinterpret_cast<float4*>(&A_lds[(ty * 4 + i) * 68 + tx * 4]) = v;
  }
  __syncthreads();

  // LN + relu + residual; wave wv handles rows wv*16..wv*16+15
  int wv = t >> 6, lane = t & 63;
  float g = ln_g_l[lane], bb = ln_b_l[lane];
#pragma unroll 4
  for (int rr = 0; rr < 16; ++rr) {
    int r = wv * 16 + rr;
    int row = m0 + r;
    float x = A_lds[r * 68 + lane];
    float mu = wave_sum(x) * (1.f / 64.f);
    float dx = x - mu;
    float var = wave_sum(dx * dx) * (1.f / 64.f);
    float y = dx * rsqrtf(var + 1e-5f) * g + bb;
    if (row < MROWS) {
      float hv = h[row * 64 + lane];
      h[row * 64 + lane] = fmaxf(y, 0.f) + hv;
    }
  }
}

// ---------- scoring MLP ----------

__global__ __launch_bounds__(256) void score_kernel(
    const int* __restrict__ ents, const float* __restrict__ h,
    const int* __restrict__ meta, const float* __restrict__ query_emb,
    const float* __restrict__ W1, const float* __restrict__ b1,
    const float* __restrict__ W2, const float* __restrict__ b2,
    float* __restrict__ out) {
  int w = (blockIdx.x * blockDim.x + threadIdx.x) >> 6;
  int lane = threadIdx.x & 63;
  if (w >= B_ * C_) return;
  int b = w / C_;
  int c = w - b * C_;
  int ps = meta[b];
  int qr = meta[B_ + b];
  int cand = ents[(b * C_ + c) * A_ + ps];
  float fv = h[(cand * B_ + b) * D_ + lane];
  float qv = query_emb[qr * D_ + lane];
  float hid0 = b1[lane];
  float hid1 = b1[D_ + lane];
#pragma unroll
  for (int k = 0; k < D_; ++k) {
    float f = rlane(fv, k);
    hid0 = fmaf(f, W1[k * FEAT_ + lane], hid0);
    hid1 = fmaf(f, W1[k * FEAT_ + D_ + lane], hid1);
  }
#pragma unroll
  for (int k = 0; k < D_; ++k) {
    float q = rlane(qv, k);
    hid0 = fmaf(q, W1[(D_ + k) * FEAT_ + lane], hid0);
    hid1 = fmaf(q, W1[(D_ + k) * FEAT_ + D_ + lane], hid1);
  }
  float accs = fmaxf(hid0, 0.f) * W2[lane] + fmaxf(hid1, 0.f) * W2[D_ + lane];
  accs = wave_sum(accs);
  if (lane == 0) out[w] = accs + b2[0];
}

// ---------- launch ----------

extern "C" void kernel_launch(void* const* d_in, const int* in_sizes, int n_in,
                              void* d_out, int out_size, void* d_ws, size_t ws_size,
                              hipStream_t stream) {
  const int* r_idx = (const int*)d_in[0];
  const int* ents = (const int*)d_in[1];
  const int* arity = (const int*)d_in[2];
  const int* edge_list = (const int*)d_in[3];
  const int* rel_list = (const int*)d_in[4];
  const float* pos_table = (const float*)d_in[5];
  const float* query_emb = (const float*)d_in[6];
  const float* rel_emb = (const float*)d_in[7];
  const float* W_agg = (const float*)d_in[8];
  const float* W_self = (const float*)d_in[9];
  const float* b_lin = (const float*)d_in[10];
  const float* ln_g = (const float*)d_in[11];
  const float* ln_b = (const float*)d_in[12];
  const float* W1 = (const float*)d_in[13];
  const float* b1 = (const float*)d_in[14];
  const float* W2 = (const float*)d_in[15];
  const float* b2 = (const float*)d_in[16];
  float* out = (float*)d_out;

  char* ws = (char*)d_ws;
  // layout (bytes):
  // h        @ 0          size 20,481,024
  // agg      @ 20,481,024 size 20,481,024
  // rel_sum  @ 40,962,048 size  5,120,256
  // pr_sum   @ 46,082,304 size  5,120,256
  // cnt/cur  @ 51,202,560 size     80,008
  // csr_off  @ 51,282,568 size     80,008
  // pairs    @ 51,362,576 size    720,000
  // meta     @ 52,082,576 size         32
  float* h = (float*)ws;
  float* agg = (float*)(ws + 20481024);
  float* rel_sum = (float*)(ws + 40962048);
  float* pr_sum = (float*)(ws + 46082304);
  int* cnt = (int*)(ws + 51202560);
  int* csr_off = (int*)(ws + 51282568);
  int* pairs = (int*)(ws + 51362576);
  int* meta = (int*)(ws + 52082576);
  if (ws_size < 52082608) return;  // insufficient scratch; output stays poisoned

  hipMemsetAsync(h, 0, (size_t)MROWS * D_ * 4, stream);
  hipMemsetAsync(cnt, 0, (N_ + 1) * sizeof(int), stream);

  init_kernel<<<B_, 256, 0, stream>>>(r_idx, ents, arity, pos_table, query_emb, h, meta);
  count_kernel<<<(E_ * A_ + 255) / 256, 256, 0, stream>>>(edge_list, cnt);
  scan_kernel<<<1, SCAN_T, 0, stream>>>(cnt, csr_off);
  fill_kernel<<<(E_ * A_ + 255) / 256, 256, 0, stream>>>(edge_list, cnt, pairs);

  for (int l = 0; l < L_; ++l) {
    const float* rel_l = rel_emb + l * R_ * D_;
    rs_kernel<<<(N_ + 3) / 4, 256, 0, stream>>>(csr_off, pairs, rel_list, pos_table,
                                                rel_l, rel_sum, pr_sum);
    agg_kernel<<<N_, 256, 0, stream>>>(csr_off, pairs, edge_list, rel_list, pos_table,
                                       rel_l, h, rel_sum, pr_sum, agg);
    sgemm_kernel<<<(MROWS + 63) / 64, 256, 0, stream>>>(
        agg, h, W_agg + l * D_ * D_, W_self + l * D_ * D_,
        b_lin + l * D_, ln_g + l * D_, ln_b + l * D_);
  }

  score_kernel<<<(B_ * C_ + 3) / 4, 256, 0, stream>>>(ents, h, meta, query_emb,
                                                      W1, b1, W2, b2, out);
  (void)in_sizes; (void)n_in; (void)out_size;
}

// Round 3
// 272.421 us; speedup vs baseline: 1.9678x; 1.7934x over previous
//
#include <hip/hip_runtime.h>

#define D_ 64
#define L_ 2
#define R_ 50
#define N_ 20001
#define A_ 6
#define E_ 30000
#define B_ 4
#define C_ 500
#define FEAT_ 128
#define MROWS (N_ * B_)  // 80004

__device__ __forceinline__ float rlane(float v, int k) {
  return __builtin_bit_cast(float, __builtin_amdgcn_readlane(__builtin_bit_cast(int, v), k));
}

__device__ __forceinline__ float wave_sum(float v) {
#pragma unroll
  for (int off = 32; off; off >>= 1) v += __shfl_xor(v, off);
  return v;
}

// ---------- init: pos_search detection + seed scatter (h layout [n][b][d]) ----------

__global__ void init_kernel(const int* __restrict__ r_idx, const int* __restrict__ ents,
                            const int* __restrict__ arity,
                            const float* __restrict__ pos_table,
                            const float* __restrict__ query_emb,
                            float* __restrict__ h, int* __restrict__ meta) {
  int b = blockIdx.x;
  int t = threadIdx.x;
  __shared__ int diff[A_];
  if (t < A_) diff[t] = 0;
  __syncthreads();
#pragma unroll
  for (int a = 0; a < A_; ++a) {
    int v0 = ents[(b * C_) * A_ + a];
    int dd = 0;
    for (int c = t; c < C_; c += blockDim.x)
      dd |= (ents[(b * C_ + c) * A_ + a] != v0);
    if (dd) diff[a] = 1;
  }
  __syncthreads();
  int ps = 0;
  for (int a = A_ - 1; a >= 0; --a)
    if (diff[a]) ps = a;
  int qr = r_idx[b * C_];
  if (t == 0) { meta[b] = ps; meta[B_ + b] = qr; }
  int ar = arity[b * C_];
  int lane = t & 63;
  for (int a = (t >> 6); a < A_; a += 4) {
    if (a < ar && a != ps) {
      int n = ents[(b * C_) * A_ + a];
      float val = query_emb[qr * D_ + lane] + pos_table[(a + 1) * D_ + lane];
      atomicAdd(&h[(n * B_ + b) * D_ + lane], val);
    }
  }
}

// ---------- CSR build (node -> incident (edge,pos) pairs) ----------

__global__ void count_kernel(const int* __restrict__ edge_list, int* __restrict__ cnt) {
  int i = blockIdx.x * blockDim.x + threadIdx.x;
  if (i >= E_ * A_) return;
  int n = edge_list[i];
  if (n) atomicAdd(&cnt[n], 1);
}

#define SCAN_T 1024
#define CHUNK 20
// reads cnt, writes off; overwrites cnt with running offsets (reused as cursor)
__global__ void scan_kernel(int* __restrict__ cnt, int* __restrict__ off) {
  __shared__ int part[SCAN_T];
  int t = threadIdx.x;
  int base = t * CHUNK;
  int v[CHUNK];
  int s = 0;
#pragma unroll
  for (int i = 0; i < CHUNK; ++i) {
    int idx = base + i;
    v[i] = (idx < N_) ? cnt[idx] : 0;
    s += v[i];
  }
  part[t] = s;
  __syncthreads();
  for (int d = 1; d < SCAN_T; d <<= 1) {
    int x = part[t];
    int y = (t >= d) ? part[t - d] : 0;
    __syncthreads();
    part[t] = x + y;
    __syncthreads();
  }
  int run = (t == 0) ? 0 : part[t - 1];
#pragma unroll
  for (int i = 0; i < CHUNK; ++i) {
    int idx = base + i;
    if (idx < N_) {
      off[idx] = run;
      cnt[idx] = run;  // cursor for fill
      run += v[i];
    }
  }
  if (t == SCAN_T - 1) off[N_] = part[SCAN_T - 1];
}

__global__ void fill_kernel(const int* __restrict__ edge_list, int* __restrict__ cur,
                            int* __restrict__ pairs) {
  int i = blockIdx.x * blockDim.x + threadIdx.x;
  if (i >= E_ * A_) return;
  int n = edge_list[i];
  if (n) {
    int p = atomicAdd(&cur[n], 1);
    pairs[p] = i;
  }
}

// ---------- per-edge sums, all batches per wave ----------
// S[e][b][d] = rel_e[d] * sum_{a: n'!=0} (h[n'][b][d] + pos[a+1][d])
// wave = edge; lane l -> (b = l>>4, d quad = (l&15)*4); one 1KB float4 gather per neighbor.

__global__ __launch_bounds__(256) void s_kernel(const int* __restrict__ edge_list,
                                                const int* __restrict__ rel_list,
                                                const float* __restrict__ pos_table,
                                                const float* __restrict__ rel_emb_l,
                                                const float* __restrict__ h,
                                                float* __restrict__ S) {
  int e = blockIdx.x * 4 + (threadIdx.x >> 6);
  int l = threadIdx.x & 63;
  int d4 = (l & 15) * 4;
  if (e >= E_) return;
  float sx = 0.f, sy = 0.f, sz = 0.f, sw = 0.f;
#pragma unroll
  for (int a = 0; a < A_; ++a) {
    int n2 = edge_list[e * A_ + a];
    if (n2) {
      float4 hv = *reinterpret_cast<const float4*>(&h[n2 * 256 + l * 4]);
      float4 pv = *reinterpret_cast<const float4*>(&pos_table[(a + 1) * D_ + d4]);
      sx += hv.x + pv.x; sy += hv.y + pv.y; sz += hv.z + pv.z; sw += hv.w + pv.w;
    }
  }
  float4 rv = *reinterpret_cast<const float4*>(&rel_emb_l[rel_list[e] * D_ + d4]);
  float4 o = make_float4(sx * rv.x, sy * rv.y, sz * rv.z, sw * rv.w);
  *reinterpret_cast<float4*>(&S[e * 256 + l * 4]) = o;
}

// ---------- fused: agg-tile gather + dual SGEMM + LN + ReLU + residual ----------
// agg[n,b] = sum_{(e,a) in csr[n]} S[e,b]  -  h[n,b]*rel_sum[n] - pr_sum[n]
// (rel_sum, pr_sum accumulated inline over the same pair loop)

__global__ __launch_bounds__(256) void sgemm_kernel(
    const int* __restrict__ csr_off, const int* __restrict__ pairs,
    const int* __restrict__ rel_list, const float* __restrict__ pos_table,
    const float* __restrict__ rel_emb_l, const float* __restrict__ S,
    float* __restrict__ h,
    const float* __restrict__ W_agg_l, const float* __restrict__ W_self_l,
    const float* __restrict__ b_lin_l, const float* __restrict__ ln_g_l,
    const float* __restrict__ ln_b_l) {
  __shared__ float A_lds[64 * 68];
  __shared__ float B_lds[64 * 64];
  int t = threadIdx.x;
  int m0 = blockIdx.x * 64;
  int nbase = m0 >> 2;  // 16 nodes per tile
  int ty = t >> 4, tx = t & 15;
  int wv = t >> 6, l = t & 63;
  int bb_ = l >> 4, d4 = (l & 15) * 4;

  // stage B = W_agg (independent of phase A)
#pragma unroll
  for (int it = 0; it < 4; ++it) {
    int k = (t >> 4) + it * 16, c4 = (t & 15) * 4;
    *reinterpret_cast<float4*>(&B_lds[k * 64 + c4]) =
        *reinterpret_cast<const float4*>(&W_agg_l[k * 64 + c4]);
  }

  // phase A: compute agg for this tile's 16 nodes directly into A_lds
#pragma unroll
  for (int q = 0; q < 4; ++q) {
    int li = wv + q * 4;
    int n = nbase + li;
    float sx = 0.f, sy = 0.f, sz = 0.f, sw = 0.f;
    float rx = 0.f, ry = 0.f, rz = 0.f, rw = 0.f;
    float px = 0.f, py = 0.f, pz = 0.f, pw = 0.f;
    float4 hv = make_float4(0.f, 0.f, 0.f, 0.f);
    if (n < N_) {
      hv = *reinterpret_cast<const float4*>(&h[n * 256 + l * 4]);
      int p0 = csr_off[n], p1 = csr_off[n + 1];
      for (int p = p0; p < p1; ++p) {
        int i = pairs[p];
        int e = i / 6, a = i - e * 6;
        float4 sv = *reinterpret_cast<const float4*>(&S[e * 256 + l * 4]);
        float4 rv = *reinterpret_cast<const float4*>(&rel_emb_l[rel_list[e] * D_ + d4]);
        float4 pv = *reinterpret_cast<const float4*>(&pos_table[(a + 1) * D_ + d4]);
        sx += sv.x; sy += sv.y; sz += sv.z; sw += sv.w;
        rx += rv.x; ry += rv.y; rz += rv.z; rw += rv.w;
        px = fmaf(pv.x, rv.x, px); py = fmaf(pv.y, rv.y, py);
        pz = fmaf(pv.z, rv.z, pz); pw = fmaf(pv.w, rv.w, pw);
      }
    }
    float4 av = make_float4(sx - hv.x * rx - px, sy - hv.y * ry - py,
                            sz - hv.z * rz - pz, sw - hv.w * rw - pw);
    *reinterpret_cast<float4*>(&A_lds[(li * 4 + bb_) * 68 + d4]) = av;
  }
  __syncthreads();

  // GEMM half 0: acc = agg @ W_agg + b_lin
  float acc[4][4];
  float4 bl = *reinterpret_cast<const float4*>(&b_lin_l[tx * 4]);
#pragma unroll
  for (int i = 0; i < 4; ++i) {
    acc[i][0] = bl.x; acc[i][1] = bl.y; acc[i][2] = bl.z; acc[i][3] = bl.w;
  }
#pragma unroll 8
  for (int k = 0; k < 64; ++k) {
    float4 b4 = *reinterpret_cast<const float4*>(&B_lds[k * 64 + tx * 4]);
    float bv[4] = {b4.x, b4.y, b4.z, b4.w};
    float avv[4];
#pragma unroll
    for (int i = 0; i < 4; ++i) avv[i] = A_lds[(ty * 4 + i) * 68 + k];
#pragma unroll
    for (int i = 0; i < 4; ++i)
#pragma unroll
      for (int j = 0; j < 4; ++j)
        acc[i][j] = fmaf(avv[i], bv[j], acc[i][j]);
  }
  __syncthreads();

  // restage: A = h tile, B = W_self
#pragma unroll
  for (int it = 0; it < 4; ++it) {
    int idx4 = t + 256 * it;
    int r = idx4 >> 4, kq = (idx4 & 15) * 4;
    int row = m0 + r;
    float4 v = make_float4(0.f, 0.f, 0.f, 0.f);
    if (row < MROWS) v = *reinterpret_cast<const float4*>(&h[row * 64 + kq]);
    *reinterpret_cast<float4*>(&A_lds[r * 68 + kq]) = v;
  }
#pragma unroll
  for (int it = 0; it < 4; ++it) {
    int k = (t >> 4) + it * 16, c4 = (t & 15) * 4;
    *reinterpret_cast<float4*>(&B_lds[k * 64 + c4]) =
        *reinterpret_cast<const float4*>(&W_self_l[k * 64 + c4]);
  }
  __syncthreads();

  // GEMM half 1: acc += h @ W_self
#pragma unroll 8
  for (int k = 0; k < 64; ++k) {
    float4 b4 = *reinterpret_cast<const float4*>(&B_lds[k * 64 + tx * 4]);
    float bv[4] = {b4.x, b4.y, b4.z, b4.w};
    float avv[4];
#pragma unroll
    for (int i = 0; i < 4; ++i) avv[i] = A_lds[(ty * 4 + i) * 68 + k];
#pragma unroll
    for (int i = 0; i < 4; ++i)
#pragma unroll
      for (int j = 0; j < 4; ++j)
        acc[i][j] = fmaf(avv[i], bv[j], acc[i][j]);
  }
  __syncthreads();

  // stage out tile
#pragma unroll
  for (int i = 0; i < 4; ++i) {
    float4 v = make_float4(acc[i][0], acc[i][1], acc[i][2], acc[i][3]);
    *reinterpret_cast<float4*>(&A_lds[(ty * 4 + i) * 68 + tx * 4]) = v;
  }
  __syncthreads();

  // LN + relu + residual
  float g = ln_g_l[l], lb = ln_b_l[l];
#pragma unroll 4
  for (int rr = 0; rr < 16; ++rr) {
    int r = wv * 16 + rr;
    int row = m0 + r;
    float x = A_lds[r * 68 + l];
    float mu = wave_sum(x) * (1.f / 64.f);
    float dx = x - mu;
    float var = wave_sum(dx * dx) * (1.f / 64.f);
    float y = dx * rsqrtf(var + 1e-5f) * g + lb;
    if (row < MROWS) {
      float hvv = h[row * 64 + l];
      h[row * 64 + l] = fmaxf(y, 0.f) + hvv;
    }
  }
}

// ---------- scoring MLP ----------

__global__ __launch_bounds__(256) void score_kernel(
    const int* __restrict__ ents, const float* __restrict__ h,
    const int* __restrict__ meta, const float* __restrict__ query_emb,
    const float* __restrict__ W1, const float* __restrict__ b1,
    const float* __restrict__ W2, const float* __restrict__ b2,
    float* __restrict__ out) {
  int w = (blockIdx.x * blockDim.x + threadIdx.x) >> 6;
  int lane = threadIdx.x & 63;
  if (w >= B_ * C_) return;
  int b = w / C_;
  int c = w - b * C_;
  int ps = meta[b];
  int qr = meta[B_ + b];
  int cand = ents[(b * C_ + c) * A_ + ps];
  float fv = h[(cand * B_ + b) * D_ + lane];
  float qv = query_emb[qr * D_ + lane];
  float hid0 = b1[lane];
  float hid1 = b1[D_ + lane];
#pragma unroll
  for (int k = 0; k < D_; ++k) {
    float f = rlane(fv, k);
    hid0 = fmaf(f, W1[k * FEAT_ + lane], hid0);
    hid1 = fmaf(f, W1[k * FEAT_ + D_ + lane], hid1);
  }
#pragma unroll
  for (int k = 0; k < D_; ++k) {
    float q = rlane(qv, k);
    hid0 = fmaf(q, W1[(D_ + k) * FEAT_ + lane], hid0);
    hid1 = fmaf(q, W1[(D_ + k) * FEAT_ + D_ + lane], hid1);
  }
  float accs = fmaxf(hid0, 0.f) * W2[lane] + fmaxf(hid1, 0.f) * W2[D_ + lane];
  accs = wave_sum(accs);
  if (lane == 0) out[w] = accs + b2[0];
}

// ---------- launch ----------

extern "C" void kernel_launch(void* const* d_in, const int* in_sizes, int n_in,
                              void* d_out, int out_size, void* d_ws, size_t ws_size,
                              hipStream_t stream) {
  const int* r_idx = (const int*)d_in[0];
  const int* ents = (const int*)d_in[1];
  const int* arity = (const int*)d_in[2];
  const int* edge_list = (const int*)d_in[3];
  const int* rel_list = (const int*)d_in[4];
  const float* pos_table = (const float*)d_in[5];
  const float* query_emb = (const float*)d_in[6];
  const float* rel_emb = (const float*)d_in[7];
  const float* W_agg = (const float*)d_in[8];
  const float* W_self = (const float*)d_in[9];
  const float* b_lin = (const float*)d_in[10];
  const float* ln_g = (const float*)d_in[11];
  const float* ln_b = (const float*)d_in[12];
  const float* W1 = (const float*)d_in[13];
  const float* b1 = (const float*)d_in[14];
  const float* W2 = (const float*)d_in[15];
  const float* b2 = (const float*)d_in[16];
  float* out = (float*)d_out;

  char* ws = (char*)d_ws;
  // layout (bytes):
  // h       @ 0           size 20,481,024
  // S       @ 20,481,024  size 30,720,000
  // cnt/cur @ 51,201,024  size     80,008
  // csr_off @ 51,281,032  size     80,008
  // pairs   @ 51,361,040  size    720,000
  // meta    @ 52,081,040  size         32
  float* h = (float*)ws;
  float* S = (float*)(ws + 20481024);
  int* cnt = (int*)(ws + 51201024);
  int* csr_off = (int*)(ws + 51281032);
  int* pairs = (int*)(ws + 51361040);
  int* meta = (int*)(ws + 52081040);
  if (ws_size < 52081072) return;  // insufficient scratch; output stays poisoned

  hipMemsetAsync(h, 0, (size_t)MROWS * D_ * 4, stream);
  hipMemsetAsync(cnt, 0, (N_ + 1) * sizeof(int), stream);

  init_kernel<<<B_, 256, 0, stream>>>(r_idx, ents, arity, pos_table, query_emb, h, meta);
  count_kernel<<<(E_ * A_ + 255) / 256, 256, 0, stream>>>(edge_list, cnt);
  scan_kernel<<<1, SCAN_T, 0, stream>>>(cnt, csr_off);
  fill_kernel<<<(E_ * A_ + 255) / 256, 256, 0, stream>>>(edge_list, cnt, pairs);

  for (int l = 0; l < L_; ++l) {
    const float* rel_l = rel_emb + l * R_ * D_;
    s_kernel<<<(E_ + 3) / 4, 256, 0, stream>>>(edge_list, rel_list, pos_table,
                                               rel_l, h, S);
    sgemm_kernel<<<(MROWS + 63) / 64, 256, 0, stream>>>(
        csr_off, pairs, rel_list, pos_table, rel_l, S, h,
        W_agg + l * D_ * D_, W_self + l * D_ * D_,
        b_lin + l * D_, ln_g + l * D_, ln_b + l * D_);
  }

  score_kernel<<<(B_ * C_ + 3) / 4, 256, 0, stream>>>(ents, h, meta, query_emb,
                                                      W1, b1, W2, b2, out);
  (void)in_sizes; (void)n_in; (void)out_size;
}

// Round 4
// 234.586 us; speedup vs baseline: 2.2852x; 1.1613x over previous
//
#include <hip/hip_runtime.h>

#define D_ 64
#define L_ 2
#define R_ 50
#define N_ 20001
#define A_ 6
#define E_ 30000
#define B_ 4
#define C_ 500
#define FEAT_ 128
#define MROWS (N_ * B_)  // 80004

__device__ __forceinline__ float rlane(float v, int k) {
  return __builtin_bit_cast(float, __builtin_amdgcn_readlane(__builtin_bit_cast(int, v), k));
}

__device__ __forceinline__ float wave_sum(float v) {
#pragma unroll
  for (int off = 32; off; off >>= 1) v += __shfl_xor(v, off);
  return v;
}

// ---------- init: pos_search detection + seed scatter (h layout [n][b][d]) ----------

__global__ void init_kernel(const int* __restrict__ r_idx, const int* __restrict__ ents,
                            const int* __restrict__ arity,
                            const float* __restrict__ pos_table,
                            const float* __restrict__ query_emb,
                            float* __restrict__ h, int* __restrict__ meta) {
  int b = blockIdx.x;
  int t = threadIdx.x;
  __shared__ int diff[A_];
  if (t < A_) diff[t] = 0;
  __syncthreads();
#pragma unroll
  for (int a = 0; a < A_; ++a) {
    int v0 = ents[(b * C_) * A_ + a];
    int dd = 0;
    for (int c = t; c < C_; c += blockDim.x)
      dd |= (ents[(b * C_ + c) * A_ + a] != v0);
    if (dd) diff[a] = 1;
  }
  __syncthreads();
  int ps = 0;
  for (int a = A_ - 1; a >= 0; --a)
    if (diff[a]) ps = a;
  int qr = r_idx[b * C_];
  if (t == 0) { meta[b] = ps; meta[B_ + b] = qr; }
  int ar = arity[b * C_];
  int lane = t & 63;
  for (int a = (t >> 6); a < A_; a += 4) {
    if (a < ar && a != ps) {
      int n = ents[(b * C_) * A_ + a];
      float val = query_emb[qr * D_ + lane] + pos_table[(a + 1) * D_ + lane];
      atomicAdd(&h[(n * B_ + b) * D_ + lane], val);
    }
  }
}

// ---------- CSR build (node -> incident (edge,pos) pairs) ----------

__global__ void count_kernel(const int* __restrict__ edge_list, int* __restrict__ cnt) {
  int i = blockIdx.x * blockDim.x + threadIdx.x;
  if (i >= E_ * A_) return;
  int n = edge_list[i];
  if (n) atomicAdd(&cnt[n], 1);
}

#define SCAN_T 1024
#define CHUNK 20
__global__ void scan_kernel(int* __restrict__ cnt, int* __restrict__ off) {
  __shared__ int part[SCAN_T];
  int t = threadIdx.x;
  int base = t * CHUNK;
  int v[CHUNK];
  int s = 0;
#pragma unroll
  for (int i = 0; i < CHUNK; ++i) {
    int idx = base + i;
    v[i] = (idx < N_) ? cnt[idx] : 0;
    s += v[i];
  }
  part[t] = s;
  __syncthreads();
  for (int d = 1; d < SCAN_T; d <<= 1) {
    int x = part[t];
    int y = (t >= d) ? part[t - d] : 0;
    __syncthreads();
    part[t] = x + y;
    __syncthreads();
  }
  int run = (t == 0) ? 0 : part[t - 1];
#pragma unroll
  for (int i = 0; i < CHUNK; ++i) {
    int idx = base + i;
    if (idx < N_) {
      off[idx] = run;
      cnt[idx] = run;  // cursor for fill
      run += v[i];
    }
  }
  if (t == SCAN_T - 1) off[N_] = part[SCAN_T - 1];
}

__global__ void fill_kernel(const int* __restrict__ edge_list, int* __restrict__ cur,
                            int* __restrict__ pairs) {
  int i = blockIdx.x * blockDim.x + threadIdx.x;
  if (i >= E_ * A_) return;
  int n = edge_list[i];
  if (n) {
    int p = atomicAdd(&cur[n], 1);
    pairs[p] = i;
  }
}

// ---------- per-edge sums, all batches per wave ----------

__global__ __launch_bounds__(256) void s_kernel(const int* __restrict__ edge_list,
                                                const int* __restrict__ rel_list,
                                                const float* __restrict__ pos_table,
                                                const float* __restrict__ rel_emb_l,
                                                const float* __restrict__ h,
                                                float* __restrict__ S) {
  int e = blockIdx.x * 4 + (threadIdx.x >> 6);
  int l = threadIdx.x & 63;
  int d4 = (l & 15) * 4;
  if (e >= E_) return;
  float sx = 0.f, sy = 0.f, sz = 0.f, sw = 0.f;
#pragma unroll
  for (int a = 0; a < A_; ++a) {
    int n2 = edge_list[e * A_ + a];
    if (n2) {
      float4 hv = *reinterpret_cast<const float4*>(&h[n2 * 256 + l * 4]);
      float4 pv = *reinterpret_cast<const float4*>(&pos_table[(a + 1) * D_ + d4]);
      sx += hv.x + pv.x; sy += hv.y + pv.y; sz += hv.z + pv.z; sw += hv.w + pv.w;
    }
  }
  float4 rv = *reinterpret_cast<const float4*>(&rel_emb_l[rel_list[e] * D_ + d4]);
  float4 o = make_float4(sx * rv.x, sy * rv.y, sz * rv.z, sw * rv.w);
  *reinterpret_cast<float4*>(&S[e * 256 + l * 4]) = o;
}

// ---------- fused: agg-tile gather + dual SGEMM + LN + ReLU + residual ----------
// 512 threads: 8 waves; phase A: 2 nodes/wave with 8-deep chunked pair gather.

__global__ __launch_bounds__(512) void sgemm_kernel(
    const int* __restrict__ csr_off, const int* __restrict__ pairs,
    const int* __restrict__ rel_list, const float* __restrict__ pos_table,
    const float* __restrict__ rel_emb_l, const float* __restrict__ S,
    float* __restrict__ h,
    const float* __restrict__ W_agg_l, const float* __restrict__ W_self_l,
    const float* __restrict__ b_lin_l, const float* __restrict__ ln_g_l,
    const float* __restrict__ ln_b_l) {
  __shared__ float A_lds[64 * 68];
  __shared__ float B_lds[64 * 64];
  int t = threadIdx.x;
  int m0 = blockIdx.x * 64;
  int nbase = m0 >> 2;  // 16 nodes per tile
  int ty = t >> 4, tx = t & 15;   // ty 0..31
  int wv = t >> 6, l = t & 63;    // wv 0..7
  int bb_ = l >> 4, d4 = (l & 15) * 4;

  // stage B = W_agg
#pragma unroll
  for (int it = 0; it < 2; ++it) {
    int idx = t + 512 * it;  // 0..1023
    int k = idx >> 4, c4 = (idx & 15) * 4;
    *reinterpret_cast<float4*>(&B_lds[k * 64 + c4]) =
        *reinterpret_cast<const float4*>(&W_agg_l[k * 64 + c4]);
  }

  // phase A: agg for 16 nodes -> A_lds; wave handles nodes wv, wv+8
#pragma unroll
  for (int q = 0; q < 2; ++q) {
    int li = wv + q * 8;
    int n = nbase + li;
    float sx = 0.f, sy = 0.f, sz = 0.f, sw = 0.f;
    float rx = 0.f, ry = 0.f, rz = 0.f, rw = 0.f;
    float px = 0.f, py = 0.f, pz = 0.f, pw = 0.f;
    float4 hv = make_float4(0.f, 0.f, 0.f, 0.f);
    if (n < N_) {
      hv = *reinterpret_cast<const float4*>(&h[n * 256 + l * 4]);
      int p0 = __builtin_amdgcn_readfirstlane(csr_off[n]);
      int p1 = __builtin_amdgcn_readfirstlane(csr_off[n + 1]);
      for (int p = p0; p < p1; p += 8) {
        int cnt = p1 - p;
        int idx8[8];
#pragma unroll
        for (int u = 0; u < 8; ++u)
          idx8[u] = (u < cnt) ? pairs[p + u] : -1;  // pairs buffer has slack; safe
#pragma unroll
        for (int u = 0; u < 8; ++u) {
          if (idx8[u] >= 0) {
            int e = idx8[u] / 6, a = idx8[u] - e * 6;
            float4 sv = *reinterpret_cast<const float4*>(&S[e * 256 + l * 4]);
            float4 rv = *reinterpret_cast<const float4*>(&rel_emb_l[rel_list[e] * D_ + d4]);
            float4 pv = *reinterpret_cast<const float4*>(&pos_table[(a + 1) * D_ + d4]);
            sx += sv.x; sy += sv.y; sz += sv.z; sw += sv.w;
            rx += rv.x; ry += rv.y; rz += rv.z; rw += rv.w;
            px = fmaf(pv.x, rv.x, px); py = fmaf(pv.y, rv.y, py);
            pz = fmaf(pv.z, rv.z, pz); pw = fmaf(pv.w, rv.w, pw);
          }
        }
      }
    }
    float4 av = make_float4(sx - hv.x * rx - px, sy - hv.y * ry - py,
                            sz - hv.z * rz - pz, sw - hv.w * rw - pw);
    *reinterpret_cast<float4*>(&A_lds[(li * 4 + bb_) * 68 + d4]) = av;
  }
  __syncthreads();

  // GEMM half 0: acc = agg @ W_agg + b_lin  (thread: rows ty*2+{0,1}, cols tx*4..+3)
  float acc[2][4];
  float4 bl = *reinterpret_cast<const float4*>(&b_lin_l[tx * 4]);
#pragma unroll
  for (int i = 0; i < 2; ++i) {
    acc[i][0] = bl.x; acc[i][1] = bl.y; acc[i][2] = bl.z; acc[i][3] = bl.w;
  }
#pragma unroll 8
  for (int k = 0; k < 64; ++k) {
    float4 b4 = *reinterpret_cast<const float4*>(&B_lds[k * 64 + tx * 4]);
    float bv[4] = {b4.x, b4.y, b4.z, b4.w};
    float a0 = A_lds[(ty * 2 + 0) * 68 + k];
    float a1 = A_lds[(ty * 2 + 1) * 68 + k];
#pragma unroll
    for (int j = 0; j < 4; ++j) {
      acc[0][j] = fmaf(a0, bv[j], acc[0][j]);
      acc[1][j] = fmaf(a1, bv[j], acc[1][j]);
    }
  }
  __syncthreads();

  // restage: A = h tile, B = W_self
#pragma unroll
  for (int it = 0; it < 2; ++it) {
    int idx4 = t + 512 * it;
    int r = idx4 >> 4, kq = (idx4 & 15) * 4;
    int row = m0 + r;
    float4 v = make_float4(0.f, 0.f, 0.f, 0.f);
    if (row < MROWS) v = *reinterpret_cast<const float4*>(&h[row * 64 + kq]);
    *reinterpret_cast<float4*>(&A_lds[r * 68 + kq]) = v;
  }
#pragma unroll
  for (int it = 0; it < 2; ++it) {
    int idx = t + 512 * it;
    int k = idx >> 4, c4 = (idx & 15) * 4;
    *reinterpret_cast<float4*>(&B_lds[k * 64 + c4]) =
        *reinterpret_cast<const float4*>(&W_self_l[k * 64 + c4]);
  }
  __syncthreads();

  // GEMM half 1: acc += h @ W_self
#pragma unroll 8
  for (int k = 0; k < 64; ++k) {
    float4 b4 = *reinterpret_cast<const float4*>(&B_lds[k * 64 + tx * 4]);
    float bv[4] = {b4.x, b4.y, b4.z, b4.w};
    float a0 = A_lds[(ty * 2 + 0) * 68 + k];
    float a1 = A_lds[(ty * 2 + 1) * 68 + k];
#pragma unroll
    for (int j = 0; j < 4; ++j) {
      acc[0][j] = fmaf(a0, bv[j], acc[0][j]);
      acc[1][j] = fmaf(a1, bv[j], acc[1][j]);
    }
  }
  __syncthreads();

  // stage out tile
#pragma unroll
  for (int i = 0; i < 2; ++i) {
    float4 v = make_float4(acc[i][0], acc[i][1], acc[i][2], acc[i][3]);
    *reinterpret_cast<float4*>(&A_lds[(ty * 2 + i) * 68 + tx * 4]) = v;
  }
  __syncthreads();

  // LN + relu + residual: wave wv handles rows wv*8..wv*8+7
  float g = ln_g_l[l], lb = ln_b_l[l];
#pragma unroll 4
  for (int rr = 0; rr < 8; ++rr) {
    int r = wv * 8 + rr;
    int row = m0 + r;
    float x = A_lds[r * 68 + l];
    float mu = wave_sum(x) * (1.f / 64.f);
    float dx = x - mu;
    float var = wave_sum(dx * dx) * (1.f / 64.f);
    float y = dx * rsqrtf(var + 1e-5f) * g + lb;
    if (row < MROWS) {
      float hvv = h[row * 64 + l];
      h[row * 64 + l] = fmaxf(y, 0.f) + hvv;
    }
  }
}

// ---------- scoring MLP ----------

__global__ __launch_bounds__(256) void score_kernel(
    const int* __restrict__ ents, const float* __restrict__ h,
    const int* __restrict__ meta, const float* __restrict__ query_emb,
    const float* __restrict__ W1, const float* __restrict__ b1,
    const float* __restrict__ W2, const float* __restrict__ b2,
    float* __restrict__ out) {
  int w = (blockIdx.x * blockDim.x + threadIdx.x) >> 6;
  int lane = threadIdx.x & 63;
  if (w >= B_ * C_) return;
  int b = w / C_;
  int c = w - b * C_;
  int ps = meta[b];
  int qr = meta[B_ + b];
  int cand = ents[(b * C_ + c) * A_ + ps];
  float fv = h[(cand * B_ + b) * D_ + lane];
  float qv = query_emb[qr * D_ + lane];
  float hid0 = b1[lane];
  float hid1 = b1[D_ + lane];
#pragma unroll
  for (int k = 0; k < D_; ++k) {
    float f = rlane(fv, k);
    hid0 = fmaf(f, W1[k * FEAT_ + lane], hid0);
    hid1 = fmaf(f, W1[k * FEAT_ + D_ + lane], hid1);
  }
#pragma unroll
  for (int k = 0; k < D_; ++k) {
    float q = rlane(qv, k);
    hid0 = fmaf(q, W1[(D_ + k) * FEAT_ + lane], hid0);
    hid1 = fmaf(q, W1[(D_ + k) * FEAT_ + D_ + lane], hid1);
  }
  float accs = fmaxf(hid0, 0.f) * W2[lane] + fmaxf(hid1, 0.f) * W2[D_ + lane];
  accs = wave_sum(accs);
  if (lane == 0) out[w] = accs + b2[0];
}

// ---------- launch ----------

extern "C" void kernel_launch(void* const* d_in, const int* in_sizes, int n_in,
                              void* d_out, int out_size, void* d_ws, size_t ws_size,
                              hipStream_t stream) {
  const int* r_idx = (const int*)d_in[0];
  const int* ents = (const int*)d_in[1];
  const int* arity = (const int*)d_in[2];
  const int* edge_list = (const int*)d_in[3];
  const int* rel_list = (const int*)d_in[4];
  const float* pos_table = (const float*)d_in[5];
  const float* query_emb = (const float*)d_in[6];
  const float* rel_emb = (const float*)d_in[7];
  const float* W_agg = (const float*)d_in[8];
  const float* W_self = (const float*)d_in[9];
  const float* b_lin = (const float*)d_in[10];
  const float* ln_g = (const float*)d_in[11];
  const float* ln_b = (const float*)d_in[12];
  const float* W1 = (const float*)d_in[13];
  const float* b1 = (const float*)d_in[14];
  const float* W2 = (const float*)d_in[15];
  const float* b2 = (const float*)d_in[16];
  float* out = (float*)d_out;

  char* ws = (char*)d_ws;
  float* h = (float*)ws;
  float* S = (float*)(ws + 20481024);
  int* cnt = (int*)(ws + 51201024);
  int* csr_off = (int*)(ws + 51281032);
  int* pairs = (int*)(ws + 51361040);
  int* meta = (int*)(ws + 52081040);
  if (ws_size < 52081072) return;  // insufficient scratch; output stays poisoned

  hipMemsetAsync(h, 0, (size_t)MROWS * D_ * 4, stream);
  hipMemsetAsync(cnt, 0, (N_ + 1) * sizeof(int), stream);

  init_kernel<<<B_, 256, 0, stream>>>(r_idx, ents, arity, pos_table, query_emb, h, meta);
  count_kernel<<<(E_ * A_ + 255) / 256, 256, 0, stream>>>(edge_list, cnt);
  scan_kernel<<<1, SCAN_T, 0, stream>>>(cnt, csr_off);
  fill_kernel<<<(E_ * A_ + 255) / 256, 256, 0, stream>>>(edge_list, cnt, pairs);

  for (int l = 0; l < L_; ++l) {
    const float* rel_l = rel_emb + l * R_ * D_;
    s_kernel<<<(E_ + 3) / 4, 256, 0, stream>>>(edge_list, rel_list, pos_table,
                                               rel_l, h, S);
    sgemm_kernel<<<(MROWS + 63) / 64, 512, 0, stream>>>(
        csr_off, pairs, rel_list, pos_table, rel_l, S, h,
        W_agg + l * D_ * D_, W_self + l * D_ * D_,
        b_lin + l * D_, ln_g + l * D_, ln_b + l * D_);
  }

  score_kernel<<<(B_ * C_ + 3) / 4, 256, 0, stream>>>(ents, h, meta, query_emb,
                                                      W1, b1, W2, b2, out);
  (void)in_sizes; (void)n_in; (void)out_size;
}